// Round 1
// baseline (25766.251 us; speedup 1.0000x reference)
//
#include <hip/hip_runtime.h>
#include <hip/hip_bf16.h>

#define SEQ   4096
#define HID   512
#define GDIM  2048           // 4*HID
#define NWG   64             // scan workgroups
#define ROWS  32             // gate-rows per WG (4 gates x 8 hidden)
#define HSL   8              // hidden units per WG

// ---------------- workspace layout (bytes) ----------------
// [0, 33554432)              : gx  [SEQ][GDIM] f32  (32 MB)
// [33554432, +2048)          : hbuf0 [512] f32
// [+2048, +4096)             : hbuf1 [512] f32
// [+4096]                    : cnt   (uint)
// [+4224]                    : flag  (uint)
#define GX_BYTES   (33554432L)
#define INIT_WORDS 1088      // zero region: 4352 B covers hbuf+cnt+flag

// =========================================================
// Kernel A: gx[t][j] = emb[tok[t]] . W_ih[j] + b_ih[j] + b_hh[j]
// 64x64 tile, BK=32, f32.  Block (0,0) also zeroes hbuf/cnt/flag.
// =========================================================
__global__ __launch_bounds__(256) void gemm_gx(
    const int*   __restrict__ tokens,
    const float* __restrict__ emb,
    const float* __restrict__ W_ih,
    const float* __restrict__ b_ih,
    const float* __restrict__ b_hh,
    float*       __restrict__ gx,
    int*         __restrict__ initzone)
{
    __shared__ float As[64][33];
    __shared__ float Bs[64][33];
    __shared__ int   tok_s[64];

    const int tid = threadIdx.x;
    const int j0  = blockIdx.x * 64;
    const int t0  = blockIdx.y * 64;

    if (blockIdx.x == 0 && blockIdx.y == 0) {
        for (int i = tid; i < INIT_WORDS; i += 256) initzone[i] = 0;
    }
    if (tid < 64) tok_s[tid] = tokens[t0 + tid];
    __syncthreads();

    const int i  = tid >> 2;        // 0..63 (row for staging loads)
    const int ko = (tid & 3) * 8;   // 0,8,16,24
    const int ty = tid >> 4;        // 0..15
    const int tx = tid & 15;        // 0..15

    const long arow = (long)tok_s[i] * HID;
    const long brow = (long)(j0 + i) * HID;

    float acc[4][4] = {};

    for (int k0 = 0; k0 < HID; k0 += 32) {
        float4 a0 = *(const float4*)&emb[arow + k0 + ko];
        float4 a1 = *(const float4*)&emb[arow + k0 + ko + 4];
        float4 b0 = *(const float4*)&W_ih[brow + k0 + ko];
        float4 b1 = *(const float4*)&W_ih[brow + k0 + ko + 4];
        // scalar LDS writes (stride-33 pad keeps reads conflict-light)
        As[i][ko+0]=a0.x; As[i][ko+1]=a0.y; As[i][ko+2]=a0.z; As[i][ko+3]=a0.w;
        As[i][ko+4]=a1.x; As[i][ko+5]=a1.y; As[i][ko+6]=a1.z; As[i][ko+7]=a1.w;
        Bs[i][ko+0]=b0.x; Bs[i][ko+1]=b0.y; Bs[i][ko+2]=b0.z; Bs[i][ko+3]=b0.w;
        Bs[i][ko+4]=b1.x; Bs[i][ko+5]=b1.y; Bs[i][ko+6]=b1.z; Bs[i][ko+7]=b1.w;
        __syncthreads();

        #pragma unroll
        for (int kk = 0; kk < 32; ++kk) {
            float av0 = As[ty*4+0][kk], av1 = As[ty*4+1][kk];
            float av2 = As[ty*4+2][kk], av3 = As[ty*4+3][kk];
            float bv0 = Bs[tx*4+0][kk], bv1 = Bs[tx*4+1][kk];
            float bv2 = Bs[tx*4+2][kk], bv3 = Bs[tx*4+3][kk];
            acc[0][0] += av0*bv0; acc[0][1] += av0*bv1; acc[0][2] += av0*bv2; acc[0][3] += av0*bv3;
            acc[1][0] += av1*bv0; acc[1][1] += av1*bv1; acc[1][2] += av1*bv2; acc[1][3] += av1*bv3;
            acc[2][0] += av2*bv0; acc[2][1] += av2*bv1; acc[2][2] += av2*bv2; acc[2][3] += av2*bv3;
            acc[3][0] += av3*bv0; acc[3][1] += av3*bv1; acc[3][2] += av3*bv2; acc[3][3] += av3*bv3;
        }
        __syncthreads();
    }

    #pragma unroll
    for (int m = 0; m < 4; ++m) {
        const long t = t0 + ty*4 + m;
        #pragma unroll
        for (int n = 0; n < 4; ++n) {
            const int j = j0 + tx*4 + n;
            gx[t*GDIM + j] = acc[m][n] + b_ih[j] + b_hh[j];
        }
    }
}

// =========================================================
// Kernel B: persistent LSTM scan.
// 64 WGs x 256 threads; WG w owns hidden units [8w, 8w+8).
// Wave wv (0..3) computes gate wv for the 8 units.
// W slice stationary in LDS as bf16 (32 KB).
// Cross-WG h exchange through MALL-coherent atomics + global barrier.
// =========================================================
__global__ __launch_bounds__(256) void lstm_scan(
    const float* __restrict__ gx,
    const float* __restrict__ W_hh,
    float*    hbuf,        // [2][512]
    unsigned* cnt,
    unsigned* flag,
    float*    out)         // [1024] = h ++ c
{
    __shared__ unsigned short Wl[ROWS][HID];  // bf16 bits
    __shared__ float hs[HID];
    __shared__ float gates_s[ROWS];
    __shared__ float cbuf[HSL];

    const int tid = threadIdx.x;
    const int w   = blockIdx.x;
    const int wv  = tid >> 6;   // wave id = gate id
    const int l   = tid & 63;   // lane

    // ---- stage W_hh slice into LDS as bf16 (RTN-even) ----
    for (int idx = tid; idx < ROWS * HID; idx += 256) {
        const int r = idx >> 9;           // 0..31
        const int c = idx & (HID - 1);
        const int j = (r >> 3) * HID + w * HSL + (r & 7);  // gate*512 + unit
        const unsigned u = __float_as_uint(W_hh[(long)j * HID + c]);
        Wl[r][c] = (unsigned short)((u + 0x7fffu + ((u >> 16) & 1u)) >> 16);
    }
    if (tid < HSL) cbuf[tid] = 0.0f;
    __syncthreads();

    const int gxbase = wv * HID + w * HSL;   // row base for this wave's gx reads

    for (int t = 0; t < SEQ; ++t) {
        // gx for this step (one row per lane 0..7 of each wave) — issued early
        float gxv = 0.0f;
        if (l < HSL) gxv = gx[(long)t * GDIM + gxbase + l];

        // broadcast h(t) from global (coherent loads, L1/L2-bypassing)
        const float* hsrc = hbuf + (t & 1) * HID;
        hs[tid]       = __hip_atomic_load(hsrc + tid,       __ATOMIC_RELAXED, __HIP_MEMORY_SCOPE_AGENT);
        hs[tid + 256] = __hip_atomic_load(hsrc + tid + 256, __ATOMIC_RELAXED, __HIP_MEMORY_SCOPE_AGENT);
        __syncthreads();

        // per-lane h chunk: k in {4l..4l+3} u {256+4l..+3} (conflict-free b128)
        const float4 hv0 = *(const float4*)&hs[4 * l];
        const float4 hv1 = *(const float4*)&hs[256 + 4 * l];

        #pragma unroll
        for (int rr = 0; rr < 8; ++rr) {
            const int r = (wv << 3) + rr;
            const uint2 wb0 = *(const uint2*)&Wl[r][4 * l];
            const uint2 wb1 = *(const uint2*)&Wl[r][256 + 4 * l];
            float acc =
                  __uint_as_float(wb0.x << 16)         * hv0.x
                + __uint_as_float(wb0.x & 0xffff0000u) * hv0.y
                + __uint_as_float(wb0.y << 16)         * hv0.z
                + __uint_as_float(wb0.y & 0xffff0000u) * hv0.w
                + __uint_as_float(wb1.x << 16)         * hv1.x
                + __uint_as_float(wb1.x & 0xffff0000u) * hv1.y
                + __uint_as_float(wb1.y << 16)         * hv1.z
                + __uint_as_float(wb1.y & 0xffff0000u) * hv1.w;
            #pragma unroll
            for (int m = 1; m < 64; m <<= 1) acc += __shfl_xor(acc, m, 64);
            if (l == rr) gates_s[r] = acc + gxv;   // lane rr's gxv == row rr
        }
        __syncthreads();

        // pointwise gates + state update (8 lanes)
        if (tid < HSL) {
            const int u = tid;
            const float gi = gates_s[u];
            const float gf = gates_s[8 + u];
            const float gc = gates_s[16 + u];
            const float go = gates_s[24 + u];
            const float ig = 1.0f / (1.0f + __expf(-gi));
            const float fg = 1.0f / (1.0f + __expf(-gf));
            const float gg = 2.0f / (1.0f + __expf(-2.0f * gc)) - 1.0f;
            const float og = 1.0f / (1.0f + __expf(-go));
            const float c  = fg * cbuf[u] + ig * gg;
            cbuf[u] = c;
            const float tc = 2.0f / (1.0f + __expf(-2.0f * c)) - 1.0f;
            const float h  = og * tc;
            float* hdst = hbuf + ((t + 1) & 1) * HID;
            __hip_atomic_store(hdst + w * HSL + u, h, __ATOMIC_RELAXED, __HIP_MEMORY_SCOPE_AGENT);
            if (t == SEQ - 1) {
                out[w * HSL + u]       = h;
                out[HID + w * HSL + u] = c;
            }
        }
        __syncthreads();   // drains the h stores (vmcnt) for the storing wave

        // ---- global barrier: monotonic counter + flag ----
        if (tid == 0) {
            const unsigned target = (unsigned)(t + 1);
            const unsigned old =
                __hip_atomic_fetch_add(cnt, 1u, __ATOMIC_ACQ_REL, __HIP_MEMORY_SCOPE_AGENT);
            if (old == (unsigned)NWG * target - 1u)
                __hip_atomic_store(flag, target, __ATOMIC_RELEASE, __HIP_MEMORY_SCOPE_AGENT);
            while (__hip_atomic_load(flag, __ATOMIC_ACQUIRE, __HIP_MEMORY_SCOPE_AGENT) < target) {
                __builtin_amdgcn_s_sleep(1);
            }
        }
        __syncthreads();
    }
}

// =========================================================
extern "C" void kernel_launch(void* const* d_in, const int* in_sizes, int n_in,
                              void* d_out, int out_size, void* d_ws, size_t ws_size,
                              hipStream_t stream)
{
    const int*   tokens = (const int*)  d_in[0];
    const float* emb    = (const float*)d_in[1];
    const float* W_ih   = (const float*)d_in[2];
    const float* W_hh   = (const float*)d_in[3];
    const float* b_ih   = (const float*)d_in[4];
    const float* b_hh   = (const float*)d_in[5];
    float* out = (float*)d_out;

    char* ws = (char*)d_ws;
    float*    gx    = (float*)ws;
    float*    hbuf  = (float*)(ws + GX_BYTES);
    unsigned* cnt   = (unsigned*)(ws + GX_BYTES + 4096);
    unsigned* flag  = (unsigned*)(ws + GX_BYTES + 4224);
    int*      initz = (int*)(ws + GX_BYTES);

    gemm_gx<<<dim3(GDIM / 64, SEQ / 64), 256, 0, stream>>>(
        tokens, emb, W_ih, b_ih, b_hh, gx, initz);

    lstm_scan<<<dim3(NWG), 256, 0, stream>>>(gx, W_hh, hbuf, cnt, flag, out);
}

// Round 2
// 15227.602 us; speedup vs baseline: 1.6921x; 1.6921x over previous
//
#include <hip/hip_runtime.h>
#include <hip/hip_bf16.h>

#define SEQ   4096
#define HID   512
#define GDIM  2048           // 4*HID
#define NWG   64             // scan workgroups
#define ROWS  32             // gate-rows per WG (4 gates x 8 hidden)
#define HSL   8              // hidden units per WG

// ---------------- workspace layout (bytes) ----------------
// [0, 33554432)       : gx  [SEQ][GDIM] f32  (32 MB)
// [33554432, +8192)   : hpair [2][512] u64  {epoch:32 | h_bits:32}
#define GX_BYTES   (33554432L)
#define INIT_WORDS 2048      // zero region: 8 KB covers both hpair parities

// =========================================================
// Kernel A: gx[t][j] = emb[tok[t]] . W_ih[j] + b_ih[j] + b_hh[j]
// 64x64 tile, BK=32, f32.  Block (0,0) also zeroes hpair.
// =========================================================
__global__ __launch_bounds__(256) void gemm_gx(
    const int*   __restrict__ tokens,
    const float* __restrict__ emb,
    const float* __restrict__ W_ih,
    const float* __restrict__ b_ih,
    const float* __restrict__ b_hh,
    float*       __restrict__ gx,
    int*         __restrict__ initzone)
{
    __shared__ float As[64][33];
    __shared__ float Bs[64][33];
    __shared__ int   tok_s[64];

    const int tid = threadIdx.x;
    const int j0  = blockIdx.x * 64;
    const int t0  = blockIdx.y * 64;

    if (blockIdx.x == 0 && blockIdx.y == 0) {
        for (int i = tid; i < INIT_WORDS; i += 256) initzone[i] = 0;
    }
    if (tid < 64) tok_s[tid] = tokens[t0 + tid];
    __syncthreads();

    const int i  = tid >> 2;        // 0..63 (row for staging loads)
    const int ko = (tid & 3) * 8;   // 0,8,16,24
    const int ty = tid >> 4;        // 0..15
    const int tx = tid & 15;        // 0..15

    const long arow = (long)tok_s[i] * HID;
    const long brow = (long)(j0 + i) * HID;

    float acc[4][4] = {};

    for (int k0 = 0; k0 < HID; k0 += 32) {
        float4 a0 = *(const float4*)&emb[arow + k0 + ko];
        float4 a1 = *(const float4*)&emb[arow + k0 + ko + 4];
        float4 b0 = *(const float4*)&W_ih[brow + k0 + ko];
        float4 b1 = *(const float4*)&W_ih[brow + k0 + ko + 4];
        As[i][ko+0]=a0.x; As[i][ko+1]=a0.y; As[i][ko+2]=a0.z; As[i][ko+3]=a0.w;
        As[i][ko+4]=a1.x; As[i][ko+5]=a1.y; As[i][ko+6]=a1.z; As[i][ko+7]=a1.w;
        Bs[i][ko+0]=b0.x; Bs[i][ko+1]=b0.y; Bs[i][ko+2]=b0.z; Bs[i][ko+3]=b0.w;
        Bs[i][ko+4]=b1.x; Bs[i][ko+5]=b1.y; Bs[i][ko+6]=b1.z; Bs[i][ko+7]=b1.w;
        __syncthreads();

        #pragma unroll
        for (int kk = 0; kk < 32; ++kk) {
            float av0 = As[ty*4+0][kk], av1 = As[ty*4+1][kk];
            float av2 = As[ty*4+2][kk], av3 = As[ty*4+3][kk];
            float bv0 = Bs[tx*4+0][kk], bv1 = Bs[tx*4+1][kk];
            float bv2 = Bs[tx*4+2][kk], bv3 = Bs[tx*4+3][kk];
            acc[0][0] += av0*bv0; acc[0][1] += av0*bv1; acc[0][2] += av0*bv2; acc[0][3] += av0*bv3;
            acc[1][0] += av1*bv0; acc[1][1] += av1*bv1; acc[1][2] += av1*bv2; acc[1][3] += av1*bv3;
            acc[2][0] += av2*bv0; acc[2][1] += av2*bv1; acc[2][2] += av2*bv2; acc[2][3] += av2*bv3;
            acc[3][0] += av3*bv0; acc[3][1] += av3*bv1; acc[3][2] += av3*bv2; acc[3][3] += av3*bv3;
        }
        __syncthreads();
    }

    #pragma unroll
    for (int m = 0; m < 4; ++m) {
        const long t = t0 + ty*4 + m;
        #pragma unroll
        for (int n = 0; n < 4; ++n) {
            const int j = j0 + tx*4 + n;
            gx[t*GDIM + j] = acc[m][n] + b_ih[j] + b_hh[j];
        }
    }
}

// =========================================================
// Kernel B: persistent LSTM scan — BARRIER-FREE.
// h published as {epoch|bits} u64 pairs; readers poll for epoch==t.
// Double-buffered by step parity; data-dependency chain bounds
// inter-WG skew to 1 step, which double buffering tolerates.
// =========================================================
__global__ __launch_bounds__(256) void lstm_scan(
    const float* __restrict__ gx,
    const float* __restrict__ W_hh,
    unsigned long long* hp,    // [2][512] {epoch:32 | h_bits:32}
    float*    out)             // [1024] = h ++ c
{
    __shared__ unsigned short Wl[ROWS][HID];  // bf16 bits
    __shared__ float hs[HID];
    __shared__ float gates_s[ROWS];
    __shared__ float cbuf[HSL];

    const int tid = threadIdx.x;
    const int w   = blockIdx.x;
    const int wv  = tid >> 6;   // wave id = gate id
    const int l   = tid & 63;   // lane

    // ---- stage W_hh slice into LDS as bf16 (RTN-even) ----
    for (int idx = tid; idx < ROWS * HID; idx += 256) {
        const int r = idx >> 9;           // 0..31
        const int c = idx & (HID - 1);
        const int j = (r >> 3) * HID + w * HSL + (r & 7);  // gate*512 + unit
        const unsigned u = __float_as_uint(W_hh[(long)j * HID + c]);
        Wl[r][c] = (unsigned short)((u + 0x7fffu + ((u >> 16) & 1u)) >> 16);
    }
    if (tid < HSL) cbuf[tid] = 0.0f;
    __syncthreads();

    const int gxbase = wv * HID + w * HSL;   // row base for this wave's gx reads
    const int i0 = 2 * tid;                  // this thread's two h slots
    const int i1 = 2 * tid + 1;

    for (int t = 0; t < SEQ; ++t) {
        // gx for this step — independent load, issue before polling
        float gxv = 0.0f;
        if (l < HSL) gxv = gx[(long)t * GDIM + gxbase + l];

        // ---- acquire h(t): poll epoch-tagged pairs (no barrier) ----
        unsigned long long* src = hp + (t & 1) * HID;
        unsigned long long v0, v1;
        do {
            v0 = __hip_atomic_load(src + i0, __ATOMIC_RELAXED, __HIP_MEMORY_SCOPE_AGENT);
        } while ((unsigned)(v0 >> 32) != (unsigned)t);
        do {
            v1 = __hip_atomic_load(src + i1, __ATOMIC_RELAXED, __HIP_MEMORY_SCOPE_AGENT);
        } while ((unsigned)(v1 >> 32) != (unsigned)t);
        hs[i0] = __uint_as_float((unsigned)v0);
        hs[i1] = __uint_as_float((unsigned)v1);
        __syncthreads();

        // per-lane h chunk: k in {4l..4l+3} u {256+4l..+3} (conflict-free b128)
        const float4 hv0 = *(const float4*)&hs[4 * l];
        const float4 hv1 = *(const float4*)&hs[256 + 4 * l];

        #pragma unroll
        for (int rr = 0; rr < 8; ++rr) {
            const int r = (wv << 3) + rr;
            const uint2 wb0 = *(const uint2*)&Wl[r][4 * l];
            const uint2 wb1 = *(const uint2*)&Wl[r][256 + 4 * l];
            float acc =
                  __uint_as_float(wb0.x << 16)         * hv0.x
                + __uint_as_float(wb0.x & 0xffff0000u) * hv0.y
                + __uint_as_float(wb0.y << 16)         * hv0.z
                + __uint_as_float(wb0.y & 0xffff0000u) * hv0.w
                + __uint_as_float(wb1.x << 16)         * hv1.x
                + __uint_as_float(wb1.x & 0xffff0000u) * hv1.y
                + __uint_as_float(wb1.y << 16)         * hv1.z
                + __uint_as_float(wb1.y & 0xffff0000u) * hv1.w;
            #pragma unroll
            for (int m = 1; m < 64; m <<= 1) acc += __shfl_xor(acc, m, 64);
            if (l == rr) gates_s[r] = acc + gxv;   // lane rr's gxv == row rr
        }
        __syncthreads();

        // pointwise gates + state update + publish (8 lanes of wave 0)
        if (tid < HSL) {
            const int u = tid;
            const float gi = gates_s[u];
            const float gf = gates_s[8 + u];
            const float gc = gates_s[16 + u];
            const float go = gates_s[24 + u];
            const float ig = 1.0f / (1.0f + __expf(-gi));
            const float fg = 1.0f / (1.0f + __expf(-gf));
            const float gg = 2.0f / (1.0f + __expf(-2.0f * gc)) - 1.0f;
            const float og = 1.0f / (1.0f + __expf(-go));
            const float c  = fg * cbuf[u] + ig * gg;
            cbuf[u] = c;
            const float tc = 2.0f / (1.0f + __expf(-2.0f * c)) - 1.0f;
            const float h  = og * tc;
            const unsigned long long pv =
                ((unsigned long long)(unsigned)(t + 1) << 32) | __float_as_uint(h);
            __hip_atomic_store(hp + ((t + 1) & 1) * HID + w * HSL + u, pv,
                               __ATOMIC_RELAXED, __HIP_MEMORY_SCOPE_AGENT);
            if (t == SEQ - 1) {
                out[w * HSL + u]       = h;
                out[HID + w * HSL + u] = c;
            }
        }
        __syncthreads();   // WAR: hs/gates_s reused next iteration
    }
}

// =========================================================
extern "C" void kernel_launch(void* const* d_in, const int* in_sizes, int n_in,
                              void* d_out, int out_size, void* d_ws, size_t ws_size,
                              hipStream_t stream)
{
    const int*   tokens = (const int*)  d_in[0];
    const float* emb    = (const float*)d_in[1];
    const float* W_ih   = (const float*)d_in[2];
    const float* W_hh   = (const float*)d_in[3];
    const float* b_ih   = (const float*)d_in[4];
    const float* b_hh   = (const float*)d_in[5];
    float* out = (float*)d_out;

    char* ws = (char*)d_ws;
    float*              gx    = (float*)ws;
    unsigned long long* hp    = (unsigned long long*)(ws + GX_BYTES);
    int*                initz = (int*)(ws + GX_BYTES);

    gemm_gx<<<dim3(GDIM / 64, SEQ / 64), 256, 0, stream>>>(
        tokens, emb, W_ih, b_ih, b_hh, gx, initz);

    lstm_scan<<<dim3(NWG), 256, 0, stream>>>(gx, W_hh, hp, out);
}